// Round 2
// baseline (1505.144 us; speedup 1.0000x reference)
//
#include <hip/hip_runtime.h>
#include <hip/hip_bf16.h>

// Spatial correlation, PATCH=9, MAX_D=4.
// in1,in2: (8,256,96,192) fp32. out: (8,9,9,96,192) fp32.
//
// Design:
//  - Block tile: 4 h-rows x 64 w-cols of output pixels, one batch.
//  - 192 threads = 3 waves; wave w = di-group {3w,3w+1,3w+2} (wave-uniform).
//  - Thread owns TW=4 consecutive w-pixels, Di=3 di, all 9 dj -> 108 f32 acc.
//  - Channels processed as 128 pairs; 8 pairs staged per chunk into LDS as
//    packed f16x2 (cvt_pkrtz), halving LDS bytes. Unpack + 2 FMA per pair.
//  - in2 LDS tile 12x72 (halo 4 each side), aligned so each di-row segment is
//    exactly 3x ds_read_b128 per thread; segment feeds 4px x 9dj = 36 pairs.

#define PATCHK 9
#define MAXD 4
#define BB 8
#define CC_TOT 256
#define HH 96
#define WW 192
#define HWSZ (HH * WW)

#define TW 4
#define NWB 16
#define WT (NWB * TW)          // 64
#define HT 4
#define DIG 3                  // di per group; 3 groups (one per wave)
#define NTHREADS (NWB * HT * DIG)   // 192
#define CPC 8                  // channel-pairs per stage chunk
#define ROWS (HT + 2 * MAXD)   // 12
#define COLS (WT + 2 * MAXD)   // 72

#define USE_FDOT2 0            // flip to 1 in a later round (v_dot2_f32_f16)

typedef __fp16 half2v __attribute__((ext_vector_type(2)));

__device__ __forceinline__ unsigned pack_h2(float a, float b) {
    half2v h = __builtin_amdgcn_cvt_pkrtz(a, b);
    return __builtin_bit_cast(unsigned, h);
}

__device__ __forceinline__ void unpack2(unsigned u, float& lo, float& hi) {
    half2v h = __builtin_bit_cast(half2v, u);
    lo = (float)h.x;
    hi = (float)h.y;
}

__launch_bounds__(NTHREADS, 3)
__global__ void corr_kernel(const float* __restrict__ in1,
                            const float* __restrict__ in2,
                            float* __restrict__ out)
{
    __shared__ unsigned s2[CPC][ROWS][COLS];   // 27648 B
    __shared__ unsigned s1[CPC][HT][WT];       //  8192 B

    const int bid  = blockIdx.x;
    const int wblk = bid % (WW / WT);               // 0..2
    const int tmp  = bid / (WW / WT);
    const int hblk = tmp % (HH / HT);               // 0..23
    const int b    = tmp / (HH / HT);               // 0..7
    const int h0   = hblk * HT;
    const int w0   = wblk * WT;

    const int tid = threadIdx.x;
    const int wb  = tid & (NWB - 1);       // 0..15
    const int hy  = (tid >> 4) & (HT - 1); // 0..3
    const int dig = tid >> 6;              // 0..2 (wave-uniform)

    const float* __restrict__ p1b = in1 + (size_t)b * CC_TOT * HWSZ;
    const float* __restrict__ p2b = in2 + (size_t)b * CC_TOT * HWSZ;

    float acc[DIG][PATCHK][TW];
    #pragma unroll
    for (int i = 0; i < DIG; ++i)
        #pragma unroll
        for (int j = 0; j < PATCHK; ++j)
            #pragma unroll
            for (int p = 0; p < TW; ++p)
                acc[i][j][p] = 0.0f;

    for (int cp0 = 0; cp0 < CC_TOT / 2; cp0 += CPC) {
        __syncthreads();

        // ---- stage in2 tile (with halo), packed f16 channel-pairs ----
        #pragma unroll 4
        for (int e = tid; e < CPC * ROWS * COLS; e += NTHREADS) {
            const int x  = e % COLS;
            const int y  = (e / COLS) % ROWS;
            const int cp = e / (COLS * ROWS);
            const int c  = (cp0 + cp) * 2;
            const int h2 = h0 + y - MAXD;
            const int w2 = w0 + x - MAXD;
            float v0 = 0.0f, v1 = 0.0f;
            if ((unsigned)h2 < (unsigned)HH && (unsigned)w2 < (unsigned)WW) {
                const size_t base = (size_t)c * HWSZ + (size_t)h2 * WW + w2;
                v0 = p2b[base];
                v1 = p2b[base + HWSZ];
            }
            s2[cp][y][x] = pack_h2(v0, v1);
        }
        // ---- stage in1 tile (no halo needed) ----
        #pragma unroll 2
        for (int e = tid; e < CPC * HT * WT; e += NTHREADS) {
            const int x  = e % WT;
            const int y  = (e / WT) % HT;
            const int cp = e / (WT * HT);
            const int c  = (cp0 + cp) * 2;
            const size_t base = (size_t)c * HWSZ + (size_t)(h0 + y) * WW + (w0 + x);
            s1[cp][y][x] = pack_h2(p1b[base], p1b[base + HWSZ]);
        }
        __syncthreads();

        // ---- compute: 8 channel-pairs x 3 di x 9 dj x 4 px ----
        #pragma unroll
        for (int cp = 0; cp < CPC; ++cp) {
            const uint4 ad = *(const uint4*)&s1[cp][hy][wb * TW];
            unsigned adw[4] = {ad.x, ad.y, ad.z, ad.w};
#if !USE_FDOT2
            float af[2 * TW];
            #pragma unroll
            for (int p = 0; p < TW; ++p) unpack2(adw[p], af[2 * p], af[2 * p + 1]);
#endif
            #pragma unroll
            for (int dil = 0; dil < DIG; ++dil) {
                const int di = dig * DIG + dil;
                const unsigned* rowp = &s2[cp][hy + di][wb * TW];
                const uint4 r0 = *(const uint4*)(rowp);
                const uint4 r1 = *(const uint4*)(rowp + 4);
                const uint4 r2 = *(const uint4*)(rowp + 8);
                const unsigned sd[12] = {r0.x, r0.y, r0.z, r0.w,
                                         r1.x, r1.y, r1.z, r1.w,
                                         r2.x, r2.y, r2.z, r2.w};
#if USE_FDOT2
                #pragma unroll
                for (int dj = 0; dj < PATCHK; ++dj)
                    #pragma unroll
                    for (int p = 0; p < TW; ++p)
                        acc[dil][dj][p] = __builtin_amdgcn_fdot2(
                            __builtin_bit_cast(half2v, adw[p]),
                            __builtin_bit_cast(half2v, sd[dj + p]),
                            acc[dil][dj][p], false);
#else
                float sf[24];
                #pragma unroll
                for (int k = 0; k < 12; ++k) unpack2(sd[k], sf[2 * k], sf[2 * k + 1]);
                #pragma unroll
                for (int dj = 0; dj < PATCHK; ++dj)
                    #pragma unroll
                    for (int p = 0; p < TW; ++p)
                        acc[dil][dj][p] += af[2 * p]     * sf[2 * (dj + p)]
                                        +  af[2 * p + 1] * sf[2 * (dj + p) + 1];
#endif
            }
        }
    }

    // ---- write out: 27 float4 stores per thread ----
    const int h = h0 + hy;
    const int wout = w0 + wb * TW;
    #pragma unroll
    for (int dil = 0; dil < DIG; ++dil) {
        const int di = dig * DIG + dil;
        #pragma unroll
        for (int dj = 0; dj < PATCHK; ++dj) {
            const size_t off =
                ((((size_t)b * PATCHK + di) * PATCHK + dj) * HH + h) * WW + wout;
            *(float4*)(out + off) = make_float4(acc[dil][dj][0], acc[dil][dj][1],
                                                acc[dil][dj][2], acc[dil][dj][3]);
        }
    }
}

extern "C" void kernel_launch(void* const* d_in, const int* in_sizes, int n_in,
                              void* d_out, int out_size, void* d_ws, size_t ws_size,
                              hipStream_t stream) {
    const float* in1 = (const float*)d_in[0];
    const float* in2 = (const float*)d_in[1];
    float* out = (float*)d_out;

    const int nblocks = BB * (HH / HT) * (WW / WT);  // 8*24*3 = 576
    corr_kernel<<<nblocks, NTHREADS, 0, stream>>>(in1, in2, out);
}